// Round 4
// baseline (2050.502 us; speedup 1.0000x reference)
//
#include <hip/hip_runtime.h>
#include <cstdint>
#include <cmath>

#define F_INN 128
#define HIDD  128
#define NCLS  40

#define BUCK_SHIFT 7
#define BUCK_NODES 128          // nodes per bucket
#define MAXBUCK 1024            // >= nbuck = ceil(N/128)
#define NSPLIT 8                // XCD split of bucket windows
#define CHUNK 8192              // edges per WG in S1/S3

typedef unsigned int u32;
typedef unsigned short u16;

static __device__ __forceinline__ float bflo(u32 u) { return __builtin_bit_cast(float, u << 16); }
static __device__ __forceinline__ float bfhi(u32 u) { return __builtin_bit_cast(float, u & 0xffff0000u); }
static __device__ __forceinline__ u16 f2bf(float f) {
    u32 u = __builtin_bit_cast(u32, f);
    return (u16)((u + 0x7fffu + ((u >> 16) & 1u)) >> 16);
}
static __device__ __forceinline__ u32 pack2(float a, float b) {
    return (u32)f2bf(a) | ((u32)f2bf(b) << 16);
}

// ---------------- S1: per-chunk bucket histogram -> global totals ----------------

__global__ __launch_bounds__(256) void k_s1(const int* __restrict__ ei, u32* __restrict__ gtot,
                                            int E, int nbuck) {
    __shared__ u32 cnt[MAXBUCK];
    int t = threadIdx.x;
    for (int i = t; i < nbuck; i += 256) cnt[i] = 0;
    __syncthreads();
    int x = blockIdx.x & (NSPLIT - 1);
    int e0 = blockIdx.x * CHUNK;
    int n = min(CHUNK, E - e0);
    const int* dst = ei + E;
    for (int i = t; i < n; i += 256)
        atomicAdd(&cnt[dst[e0 + i] >> BUCK_SHIFT], 1u);
    __syncthreads();
    for (int b = t; b < nbuck; b += 256) {
        u32 c = cnt[b];
        if (c) atomicAdd(&gtot[(b << 3) | x], c);
    }
}

// ---------------- S2: exclusive scan of (nbuck*8) totals -> base, cursor ----------------
// single workgroup, 256 threads x 32 elements (m <= 8192)

__global__ __launch_bounds__(256) void k_s2(const u32* __restrict__ gtot, u32* __restrict__ base,
                                            u32* __restrict__ cursor, int m) {
    __shared__ u32 part[256];
    int t = threadIdx.x;
    u32 local[32];
    u32 s = 0;
#pragma unroll
    for (int j = 0; j < 32; ++j) {
        int i = t * 32 + j;
        u32 v = (i < m) ? gtot[i] : 0u;
        local[j] = s;
        s += v;
    }
    part[t] = s;
    __syncthreads();
    for (int off = 1; off < 256; off <<= 1) {
        u32 v = (t >= off) ? part[t - off] : 0u;
        __syncthreads();
        part[t] += v;
        __syncthreads();
    }
    u32 pre = (t == 0) ? 0u : part[t - 1];
#pragma unroll
    for (int j = 0; j < 32; ++j) {
        int i = t * 32 + j;
        if (i < m) { u32 bb = pre + local[j]; base[i] = bb; cursor[i] = bb; }
    }
    if (t == 255) base[m] = part[255];   // = E
}

// ---------------- S3: scatter edges into bucket windows (bulk reservation) ----------------

__global__ __launch_bounds__(256) void k_s3(const int* __restrict__ ei, u32* __restrict__ cursor,
                                            u32* __restrict__ arr, int E, int nbuck) {
    __shared__ u32 cnt[MAXBUCK];
    __shared__ u32 lbase[MAXBUCK];
    int t = threadIdx.x;
    for (int i = t; i < nbuck; i += 256) cnt[i] = 0;
    __syncthreads();
    int x = blockIdx.x & (NSPLIT - 1);
    int e0 = blockIdx.x * CHUNK;
    int n = min(CHUNK, E - e0);
    const int* src = ei;
    const int* dst = ei + E;
    for (int i = t; i < n; i += 256)
        atomicAdd(&cnt[dst[e0 + i] >> BUCK_SHIFT], 1u);
    __syncthreads();
    for (int b = t; b < nbuck; b += 256) {
        u32 c = cnt[b];
        lbase[b] = c ? atomicAdd(&cursor[(b << 3) | x], c) : 0u;
    }
    __syncthreads();
    for (int i = t; i < nbuck; i += 256) cnt[i] = 0;
    __syncthreads();
    for (int i = t; i < n; i += 256) {
        int s = src[e0 + i], d = dst[e0 + i];
        int b = d >> BUCK_SHIFT;
        u32 off = atomicAdd(&cnt[b], 1u);
        arr[lbase[b] + off] = ((u32)s << BUCK_SHIFT) | (u32)(d & (BUCK_NODES - 1));
    }
}

// ---------------- S4: per-bucket degree -> dinv ----------------

__global__ __launch_bounds__(256) void k_s4(const u32* __restrict__ arr, const u32* __restrict__ base,
                                            float* __restrict__ dinv, int N) {
    __shared__ u32 cnt[BUCK_NODES];
    int b = blockIdx.x, t = threadIdx.x;
    if (t < BUCK_NODES) cnt[t] = 0;
    __syncthreads();
    u32 s0 = base[b << 3], s1 = base[(b + 1) << 3];
    for (u32 i = s0 + t; i < s1; i += 256)
        atomicAdd(&cnt[arr[i] & (u32)(BUCK_NODES - 1)], 1u);
    __syncthreads();
    int node = (b << BUCK_SHIFT) + t;
    if (t < BUCK_NODES && node < N)
        dinv[node] = rsqrtf((float)(cnt[t] + 1));   // +1 self loop
}

// ---------------- GEMM1: H1 = bf16( X @ W1 )  (unchanged, verified) ----------------

__global__ __launch_bounds__(256) void k_gemm1(const float* __restrict__ X, const float* __restrict__ W,
                                               u32* __restrict__ H, int M) {
    __shared__ float ws[128 * 128];
    __shared__ float xs[32][128];
    int tid = threadIdx.x;
    for (int i = tid * 4; i < 128 * 128; i += 1024)
        *(float4*)&ws[i] = *(const float4*)&W[i];
    int row0 = blockIdx.x * 32;
    for (int i = tid; i < 32 * 32; i += 256) {
        int r = i >> 5, c4 = (i & 31) << 2;
        int gr = row0 + r;
        float4 v = (gr < M) ? *(const float4*)&X[(size_t)gr * 128 + c4] : make_float4(0.f, 0.f, 0.f, 0.f);
        *(float4*)&xs[r][c4] = v;
    }
    __syncthreads();
    int tx = tid & 31, ty = tid >> 5;
    int c0 = tx << 2;
    int r0 = ty << 2;
    float acc[4][4] = {};
#define ROWFMA(r, xr) { acc[r][0] += (xr) * wv.x; acc[r][1] += (xr) * wv.y; acc[r][2] += (xr) * wv.z; acc[r][3] += (xr) * wv.w; }
    for (int k0 = 0; k0 < 128; k0 += 4) {
        float4 xv0 = *(float4*)&xs[r0 + 0][k0];
        float4 xv1 = *(float4*)&xs[r0 + 1][k0];
        float4 xv2 = *(float4*)&xs[r0 + 2][k0];
        float4 xv3 = *(float4*)&xs[r0 + 3][k0];
#pragma unroll
        for (int kk = 0; kk < 4; ++kk) {
            float4 wv = *(float4*)&ws[(k0 + kk) * 128 + c0];
            float x0 = kk == 0 ? xv0.x : kk == 1 ? xv0.y : kk == 2 ? xv0.z : xv0.w;
            float x1 = kk == 0 ? xv1.x : kk == 1 ? xv1.y : kk == 2 ? xv1.z : xv1.w;
            float x2 = kk == 0 ? xv2.x : kk == 1 ? xv2.y : kk == 2 ? xv2.z : xv2.w;
            float x3 = kk == 0 ? xv3.x : kk == 1 ? xv3.y : kk == 2 ? xv3.z : xv3.w;
            ROWFMA(0, x0) ROWFMA(1, x1) ROWFMA(2, x2) ROWFMA(3, x3)
        }
    }
#undef ROWFMA
#pragma unroll
    for (int rr = 0; rr < 4; ++rr) {
        int gr = row0 + r0 + rr;
        if (gr < M) {
            u32 w0 = pack2(acc[rr][0], acc[rr][1]);
            u32 w1 = pack2(acc[rr][2], acc[rr][3]);
            uint2 o; o.x = w0; o.y = w1;
            *(uint2*)&H[(size_t)gr * 64 + (c0 >> 1)] = o;
        }
    }
}

// ---------------- AGG1 push: A1 = bf16(relu(Ahat @ H1 + b1)), per-bucket LDS accumulate ----------------
// 512 thr; acc[128 nodes][64 feats] f32 = 32KB; two passes over features (p=0,1).
// half-wave (32 lanes) per edge: lane l reads u32 l of the half-row.

__global__ __launch_bounds__(512) void k_agg1p(const u32* __restrict__ H1, const u32* __restrict__ arr,
                                               const u32* __restrict__ base, const float* __restrict__ dinv,
                                               const float* __restrict__ b1, u32* __restrict__ A1,
                                               int N) {
    __shared__ float acc[BUCK_NODES][64];
    __shared__ float dl[BUCK_NODES];
    int b = blockIdx.x, t = threadIdx.x;
    int node0 = b << BUCK_SHIFT;
    if (t < BUCK_NODES) {
        int gn = node0 + t;
        dl[t] = (gn < N) ? dinv[gn] : 0.f;
    }
    u32 s0 = base[b << 3], s1 = base[(b + 1) << 3];
    int lane = t & 63;
    int half = lane >> 5;       // which edge of the wave's pair
    int l = lane & 31;          // u32 index in half-row
    int wv = t >> 6;            // wave 0..7

    for (int p = 0; p < 2; ++p) {
        __syncthreads();
        // init: self-loop contribution (dl available after first barrier)
        for (int i = t; i < BUCK_NODES * 32; i += 512) {
            int nn = i >> 5, c = i & 31;
            int gn = node0 + nn;
            float vx = 0.f, vy = 0.f;
            if (gn < N) {
                u32 u = H1[(size_t)gn * 64 + p * 32 + c];
                float w = dl[nn] * dl[nn];
                vx = w * bflo(u); vy = w * bfhi(u);
            }
            acc[nn][2 * c] = vx;
            acc[nn][2 * c + 1] = vy;
        }
        __syncthreads();
        // edge accumulation
        for (u32 i = s0 + (u32)(wv * 2 + half); i < s1; i += 16) {
            u32 pk = arr[i];
            int src = (int)(pk >> BUCK_SHIFT);
            int d = (int)(pk & (u32)(BUCK_NODES - 1));
            float w = dinv[src] * dl[d];
            u32 u = H1[(size_t)src * 64 + p * 32 + l];
            atomicAdd(&acc[d][2 * l], w * bflo(u));
            atomicAdd(&acc[d][2 * l + 1], w * bfhi(u));
        }
        __syncthreads();
        // epilogue: bias + relu + pack to bf16
        for (int i = t; i < BUCK_NODES * 32; i += 512) {
            int nn = i >> 5, c = i & 31;
            int gn = node0 + nn;
            if (gn < N) {
                float ax = fmaxf(acc[nn][2 * c] + b1[p * 64 + 2 * c], 0.f);
                float ay = fmaxf(acc[nn][2 * c + 1] + b1[p * 64 + 2 * c + 1], 0.f);
                A1[(size_t)gn * 64 + p * 32 + c] = pack2(ax, ay);
            }
        }
    }
}

// ---------------- GEMM2: H2 = bf16( A1 @ W2 ), H2 row = 32 u32 (40 bf16 used) ----------------

__global__ __launch_bounds__(256) void k_gemm2(const u32* __restrict__ A, const float* __restrict__ W,
                                               u32* __restrict__ H, int M) {
    __shared__ float ws[128 * 40];
    __shared__ float xs[64][130];
    int tid = threadIdx.x;
    for (int i = tid * 4; i < 128 * 40; i += 1024)
        *(float4*)&ws[i] = *(const float4*)&W[i];
    int row0 = blockIdx.x * 64;
    for (int i = tid; i < 64 * 64; i += 256) {
        int r = i >> 6, cu = i & 63;
        int gr = row0 + r;
        u32 u = (gr < M) ? A[(size_t)gr * 64 + cu] : 0u;
        xs[r][cu * 2] = bflo(u);
        xs[r][cu * 2 + 1] = bfhi(u);
    }
    __syncthreads();
    int tx = tid & 7, ty = tid >> 3;
    int c0 = tx * 5;
    int r0 = ty * 2;
    float acc[2][5] = {};
#pragma unroll 8
    for (int k = 0; k < 128; ++k) {
        float x0 = xs[r0][k], x1 = xs[r0 + 1][k];
#pragma unroll
        for (int j = 0; j < 5; ++j) {
            float w = ws[k * 40 + c0 + j];
            acc[0][j] += x0 * w;
            acc[1][j] += x1 * w;
        }
    }
    u16* Hs = (u16*)H;
#pragma unroll
    for (int rr = 0; rr < 2; ++rr) {
        int gr = row0 + r0 + rr;
        if (gr < M) {
#pragma unroll
            for (int j = 0; j < 5; ++j) Hs[(size_t)gr * 64 + c0 + j] = f2bf(acc[rr][j]);
        }
    }
}

// ---------------- AGG2 push + bias + log_softmax: per-bucket LDS accumulate ----------------
// acc[128 nodes][40] f32 = 20KB. half-wave per edge, lanes l<20 read u32 l of H2 row.

__global__ __launch_bounds__(512) void k_agg2p(const u32* __restrict__ H2, const u32* __restrict__ arr,
                                               const u32* __restrict__ base, const float* __restrict__ dinv,
                                               const float* __restrict__ b2, float* __restrict__ out,
                                               int N) {
    __shared__ float acc[BUCK_NODES][40];
    __shared__ float dl[BUCK_NODES];
    __shared__ float b2l[NCLS];
    int b = blockIdx.x, t = threadIdx.x;
    int node0 = b << BUCK_SHIFT;
    if (t < BUCK_NODES) {
        int gn = node0 + t;
        dl[t] = (gn < N) ? dinv[gn] : 0.f;
    }
    if (t < NCLS) b2l[t] = b2[t];
    u32 s0 = base[b << 3], s1 = base[(b + 1) << 3];
    int lane = t & 63;
    int half = lane >> 5;
    int l = lane & 31;
    int wv = t >> 6;
    __syncthreads();
    // init: self-loop contribution
    for (int i = t; i < BUCK_NODES * 32; i += 512) {
        int nn = i >> 5, c = i & 31;
        if (c < 20) {
            int gn = node0 + nn;
            float vx = 0.f, vy = 0.f;
            if (gn < N) {
                u32 u = H2[(size_t)gn * 32 + c];
                float w = dl[nn] * dl[nn];
                vx = w * bflo(u); vy = w * bfhi(u);
            }
            acc[nn][2 * c] = vx;
            acc[nn][2 * c + 1] = vy;
        }
    }
    __syncthreads();
    for (u32 i = s0 + (u32)(wv * 2 + half); i < s1; i += 16) {
        u32 pk = arr[i];
        int src = (int)(pk >> BUCK_SHIFT);
        int d = (int)(pk & (u32)(BUCK_NODES - 1));
        float w = dinv[src] * dl[d];
        if (l < 20) {
            u32 u = H2[(size_t)src * 32 + l];
            atomicAdd(&acc[d][2 * l], w * bflo(u));
            atomicAdd(&acc[d][2 * l + 1], w * bfhi(u));
        }
    }
    __syncthreads();
    // log-softmax per node (threads 0..127, one node each)
    if (t < BUCK_NODES) {
        int gn = node0 + t;
        if (gn < N) {
            float m = -INFINITY;
#pragma unroll
            for (int i = 0; i < NCLS; ++i) m = fmaxf(m, acc[t][i] + b2l[i]);
            float ex = 0.f;
#pragma unroll
            for (int i = 0; i < NCLS; ++i) ex += expf(acc[t][i] + b2l[i] - m);
            float ls = logf(ex) + m;
#pragma unroll
            for (int i = 0; i < NCLS; ++i) out[(size_t)gn * NCLS + i] = acc[t][i] + b2l[i] - ls;
        }
    }
}

// ---------------- launch ----------------

extern "C" void kernel_launch(void* const* d_in, const int* in_sizes, int n_in,
                              void* d_out, int out_size, void* d_ws, size_t ws_size,
                              hipStream_t stream) {
    const float* X  = (const float*)d_in[0];
    const int*   EI = (const int*)d_in[1];
    const float* W1 = (const float*)d_in[2];
    const float* B1 = (const float*)d_in[3];
    const float* W2 = (const float*)d_in[4];
    const float* B2 = (const float*)d_in[5];
    float* OUT = (float*)d_out;

    const int N = in_sizes[0] / F_INN;        // 100000
    const int E = in_sizes[1] / 2;            // 1600000
    const int nbuck = (N + BUCK_NODES - 1) >> BUCK_SHIFT;   // 782
    const int m = nbuck * NSPLIT;             // 6256 window slots

    char* ws = (char*)d_ws;
    size_t off = 0;
    auto alloc = [&](size_t bytes) -> void* {
        off = (off + 255) & ~(size_t)255;
        void* p = ws + off;
        off += bytes;
        return p;
    };
    u32*   H1     = (u32*)  alloc((size_t)N * 64 * 4);    // 25.6 MB
    u32*   A1     = (u32*)  alloc((size_t)N * 64 * 4);    // 25.6 MB
    u32*   H2     = (u32*)  alloc((size_t)N * 32 * 4);    // 12.8 MB
    float* dinv   = (float*)alloc((size_t)N * 4);
    u32*   gtot   = (u32*)  alloc((size_t)(m + 1) * 4);
    u32*   base   = (u32*)  alloc((size_t)(m + 1) * 4);
    u32*   cursor = (u32*)  alloc((size_t)m * 4);
    u32*   arr    = (u32*)  alloc((size_t)E * 4);         // 6.4 MB packed edges

    hipMemsetAsync(gtot, 0, (size_t)m * 4, stream);

    int nchunk = (E + CHUNK - 1) / CHUNK;     // 196

    k_s1<<<nchunk, 256, 0, stream>>>(EI, gtot, E, nbuck);
    k_s2<<<1, 256, 0, stream>>>(gtot, base, cursor, m);
    k_s3<<<nchunk, 256, 0, stream>>>(EI, cursor, arr, E, nbuck);
    k_s4<<<nbuck, 256, 0, stream>>>(arr, base, dinv, N);

    k_gemm1<<<(N + 31) / 32, 256, 0, stream>>>(X, W1, H1, N);
    k_agg1p<<<nbuck, 512, 0, stream>>>(H1, arr, base, dinv, B1, A1, N);
    k_gemm2<<<(N + 63) / 64, 256, 0, stream>>>(A1, W2, H2, N);
    k_agg2p<<<nbuck, 512, 0, stream>>>(H2, arr, base, dinv, B2, OUT, N);
}

// Round 5
// 462.284 us; speedup vs baseline: 4.4356x; 4.4356x over previous
//
#include <hip/hip_runtime.h>
#include <cstdint>
#include <cmath>

#define F_INN 128
#define HIDD  128
#define NCLS  40

#define BUCK_SHIFT 7
#define BUCK_NODES 128          // nodes per bucket
#define MAXBUCK 1024            // >= nbuck = ceil(N/128)
#define NSPLIT 8                // XCD split of bucket windows (x = blockIdx&7)
#define CHUNK 8192              // edges per WG in S1/S3

typedef unsigned int u32;
typedef unsigned short u16;

static __device__ __forceinline__ float bflo(u32 u) { return __builtin_bit_cast(float, u << 16); }
static __device__ __forceinline__ float bfhi(u32 u) { return __builtin_bit_cast(float, u & 0xffff0000u); }
static __device__ __forceinline__ u16 f2bf(float f) {
    u32 u = __builtin_bit_cast(u32, f);
    return (u16)((u + 0x7fffu + ((u >> 16) & 1u)) >> 16);
}
static __device__ __forceinline__ u32 pack2(float a, float b) {
    return (u32)f2bf(a) | ((u32)f2bf(b) << 16);
}

// ---------------- S1: per-chunk bucket histogram -> global per-(bucket,xcd-slot) totals ----------------

__global__ __launch_bounds__(256) void k_s1(const int* __restrict__ ei, u32* __restrict__ gtot,
                                            int E, int nbuck) {
    __shared__ u32 cnt[MAXBUCK];
    int t = threadIdx.x;
    for (int i = t; i < nbuck; i += 256) cnt[i] = 0;
    __syncthreads();
    int x = blockIdx.x & (NSPLIT - 1);
    int e0 = blockIdx.x * CHUNK;
    int n = min(CHUNK, E - e0);
    const int* dst = ei + E;
    for (int i = t; i < n; i += 256)
        atomicAdd(&cnt[dst[e0 + i] >> BUCK_SHIFT], 1u);
    __syncthreads();
    for (int b = t; b < nbuck; b += 256) {
        u32 c = cnt[b];
        if (c) atomicAdd(&gtot[(b << 3) | x], c);
    }
}

// ---------------- S2: exclusive scan of (nbuck*8) totals -> base, cursor ----------------

__global__ __launch_bounds__(256) void k_s2(const u32* __restrict__ gtot, u32* __restrict__ base,
                                            u32* __restrict__ cursor, int m) {
    __shared__ u32 part[256];
    int t = threadIdx.x;
    u32 local[32];
    u32 s = 0;
#pragma unroll
    for (int j = 0; j < 32; ++j) {
        int i = t * 32 + j;
        u32 v = (i < m) ? gtot[i] : 0u;
        local[j] = s;
        s += v;
    }
    part[t] = s;
    __syncthreads();
    for (int off = 1; off < 256; off <<= 1) {
        u32 v = (t >= off) ? part[t - off] : 0u;
        __syncthreads();
        part[t] += v;
        __syncthreads();
    }
    u32 pre = (t == 0) ? 0u : part[t - 1];
#pragma unroll
    for (int j = 0; j < 32; ++j) {
        int i = t * 32 + j;
        if (i < m) { u32 bb = pre + local[j]; base[i] = bb; cursor[i] = bb; }
    }
    if (t == 255) base[m] = part[255];   // = E
}

// ---------------- S3: scatter packed edges into bucket sub-windows (bulk reservation) ----------------

__global__ __launch_bounds__(256) void k_s3(const int* __restrict__ ei, u32* __restrict__ cursor,
                                            u32* __restrict__ arr, int E, int nbuck) {
    __shared__ u32 cnt[MAXBUCK];
    __shared__ u32 lbase[MAXBUCK];
    int t = threadIdx.x;
    for (int i = t; i < nbuck; i += 256) cnt[i] = 0;
    __syncthreads();
    int x = blockIdx.x & (NSPLIT - 1);
    int e0 = blockIdx.x * CHUNK;
    int n = min(CHUNK, E - e0);
    const int* src = ei;
    const int* dst = ei + E;
    for (int i = t; i < n; i += 256)
        atomicAdd(&cnt[dst[e0 + i] >> BUCK_SHIFT], 1u);
    __syncthreads();
    for (int b = t; b < nbuck; b += 256) {
        u32 c = cnt[b];
        lbase[b] = c ? atomicAdd(&cursor[(b << 3) | x], c) : 0u;
    }
    __syncthreads();
    for (int i = t; i < nbuck; i += 256) cnt[i] = 0;
    __syncthreads();
    for (int i = t; i < n; i += 256) {
        int s = src[e0 + i], d = dst[e0 + i];
        int b = d >> BUCK_SHIFT;
        u32 off = atomicAdd(&cnt[b], 1u);
        arr[lbase[b] + off] = ((u32)s << BUCK_SHIFT) | (u32)(d & (BUCK_NODES - 1));
    }
}

// ---------------- SORT: per-bucket counting sort -> dense csr + rowptr + dinv ----------------
// One block per bucket. Reads its window twice (hist, scatter); all global writes dense.

__global__ __launch_bounds__(256) void k_sortb(const u32* __restrict__ arr, const u32* __restrict__ base,
                                               int* __restrict__ csr, int* __restrict__ rowptr,
                                               float* __restrict__ dinv, int N, int nbuck) {
    __shared__ u32 cnt[BUCK_NODES];
    __shared__ u32 ex[BUCK_NODES];
    __shared__ u32 cur[BUCK_NODES];
    int b = blockIdx.x, t = threadIdx.x;
    int node0 = b << BUCK_SHIFT;
    if (t < BUCK_NODES) cnt[t] = 0;
    __syncthreads();
    u32 s0 = base[b << 3], s1 = base[(b + 1) << 3];
    for (u32 i = s0 + t; i < s1; i += 256)
        atomicAdd(&cnt[arr[i] & (u32)(BUCK_NODES - 1)], 1u);
    __syncthreads();
    if (t < BUCK_NODES) ex[t] = cnt[t];
    __syncthreads();
    for (int off = 1; off < BUCK_NODES; off <<= 1) {
        u32 v = 0;
        if (t < BUCK_NODES && t >= off) v = ex[t - off];
        __syncthreads();
        if (t < BUCK_NODES) ex[t] += v;
        __syncthreads();
    }
    // ex = inclusive prefix; exclusive = ex - cnt
    if (t < BUCK_NODES) {
        int node = node0 + t;
        u32 excl = ex[t] - cnt[t];
        cur[t] = s0 + excl;
        if (node <= N) rowptr[node] = (int)(s0 + excl);
        if (node < N) dinv[node] = rsqrtf((float)(cnt[t] + 1));  // +1 self loop
    }
    if (t == 0 && b == nbuck - 1) rowptr[N] = (int)s1;
    __syncthreads();
    for (u32 i = s0 + t; i < s1; i += 256) {
        u32 pk = arr[i];
        int d = (int)(pk & (u32)(BUCK_NODES - 1));
        u32 pos = atomicAdd(&cur[d], 1u);
        csr[pos] = (int)(pk >> BUCK_SHIFT);
    }
}

// ---------------- GEMM1: H1 = bf16( X @ W1 )  (verified R3) ----------------

__global__ __launch_bounds__(256) void k_gemm1(const float* __restrict__ X, const float* __restrict__ W,
                                               u32* __restrict__ H, int M) {
    __shared__ float ws[128 * 128];
    __shared__ float xs[32][128];
    int tid = threadIdx.x;
    for (int i = tid * 4; i < 128 * 128; i += 1024)
        *(float4*)&ws[i] = *(const float4*)&W[i];
    int row0 = blockIdx.x * 32;
    for (int i = tid; i < 32 * 32; i += 256) {
        int r = i >> 5, c4 = (i & 31) << 2;
        int gr = row0 + r;
        float4 v = (gr < M) ? *(const float4*)&X[(size_t)gr * 128 + c4] : make_float4(0.f, 0.f, 0.f, 0.f);
        *(float4*)&xs[r][c4] = v;
    }
    __syncthreads();
    int tx = tid & 31, ty = tid >> 5;
    int c0 = tx << 2;
    int r0 = ty << 2;
    float acc[4][4] = {};
#define ROWFMA(r, xr) { acc[r][0] += (xr) * wv.x; acc[r][1] += (xr) * wv.y; acc[r][2] += (xr) * wv.z; acc[r][3] += (xr) * wv.w; }
    for (int k0 = 0; k0 < 128; k0 += 4) {
        float4 xv0 = *(float4*)&xs[r0 + 0][k0];
        float4 xv1 = *(float4*)&xs[r0 + 1][k0];
        float4 xv2 = *(float4*)&xs[r0 + 2][k0];
        float4 xv3 = *(float4*)&xs[r0 + 3][k0];
#pragma unroll
        for (int kk = 0; kk < 4; ++kk) {
            float4 wv = *(float4*)&ws[(k0 + kk) * 128 + c0];
            float x0 = kk == 0 ? xv0.x : kk == 1 ? xv0.y : kk == 2 ? xv0.z : xv0.w;
            float x1 = kk == 0 ? xv1.x : kk == 1 ? xv1.y : kk == 2 ? xv1.z : xv1.w;
            float x2 = kk == 0 ? xv2.x : kk == 1 ? xv2.y : kk == 2 ? xv2.z : xv2.w;
            float x3 = kk == 0 ? xv3.x : kk == 1 ? xv3.y : kk == 2 ? xv3.z : xv3.w;
            ROWFMA(0, x0) ROWFMA(1, x1) ROWFMA(2, x2) ROWFMA(3, x3)
        }
    }
#undef ROWFMA
#pragma unroll
    for (int rr = 0; rr < 4; ++rr) {
        int gr = row0 + r0 + rr;
        if (gr < M) {
            u32 w0 = pack2(acc[rr][0], acc[rr][1]);
            u32 w1 = pack2(acc[rr][2], acc[rr][3]);
            uint2 o; o.x = w0; o.y = w1;
            *(uint2*)&H[(size_t)gr * 64 + (c0 >> 1)] = o;
        }
    }
}

// ---------------- GEMM2: H2 = bf16( A1 @ W2 )  (verified R3; row = 32 u32) ----------------

__global__ __launch_bounds__(256) void k_gemm2(const u32* __restrict__ A, const float* __restrict__ W,
                                               u32* __restrict__ H, int M) {
    __shared__ float ws[128 * 40];
    __shared__ float xs[64][130];
    int tid = threadIdx.x;
    for (int i = tid * 4; i < 128 * 40; i += 1024)
        *(float4*)&ws[i] = *(const float4*)&W[i];
    int row0 = blockIdx.x * 64;
    for (int i = tid; i < 64 * 64; i += 256) {
        int r = i >> 6, cu = i & 63;
        int gr = row0 + r;
        u32 u = (gr < M) ? A[(size_t)gr * 64 + cu] : 0u;
        xs[r][cu * 2] = bflo(u);
        xs[r][cu * 2 + 1] = bfhi(u);
    }
    __syncthreads();
    int tx = tid & 7, ty = tid >> 3;
    int c0 = tx * 5;
    int r0 = ty * 2;
    float acc[2][5] = {};
#pragma unroll 8
    for (int k = 0; k < 128; ++k) {
        float x0 = xs[r0][k], x1 = xs[r0 + 1][k];
#pragma unroll
        for (int j = 0; j < 5; ++j) {
            float w = ws[k * 40 + c0 + j];
            acc[0][j] += x0 * w;
            acc[1][j] += x1 * w;
        }
    }
    u16* Hs = (u16*)H;
#pragma unroll
    for (int rr = 0; rr < 2; ++rr) {
        int gr = row0 + r0 + rr;
        if (gr < M) {
#pragma unroll
            for (int j = 0; j < 5; ++j) Hs[(size_t)gr * 64 + c0 + j] = f2bf(acc[rr][j]);
        }
    }
}

// ---------------- AGG1 (verified R3, pull): A1 = bf16(relu(Ahat @ H1 + b1)) ----------------

__global__ __launch_bounds__(256) void k_agg1(const u32* __restrict__ H1, const int* __restrict__ csr,
                                              const int* __restrict__ rowptr, const float* __restrict__ dinv,
                                              const float* __restrict__ b1, u32* __restrict__ A1, int n) {
    int node = (int)((blockIdx.x * 256 + threadIdx.x) >> 6);
    int lane = threadIdx.x & 63;
    if (node >= n) return;
    float di = dinv[node];
    u32 us = H1[(size_t)node * 64 + lane];
    float wself = di * di;
    float ax = wself * bflo(us), ay = wself * bfhi(us);
    int e0 = rowptr[node], e1 = rowptr[node + 1];
    int e = e0;
    for (; e + 1 < e1; e += 2) {
        int s0 = csr[e], s1 = csr[e + 1];
        float w0 = dinv[s0] * di, w1 = dinv[s1] * di;
        u32 u0 = H1[(size_t)s0 * 64 + lane];
        u32 u1 = H1[(size_t)s1 * 64 + lane];
        ax += w0 * bflo(u0) + w1 * bflo(u1);
        ay += w0 * bfhi(u0) + w1 * bfhi(u1);
    }
    if (e < e1) {
        int s0 = csr[e];
        float w0 = dinv[s0] * di;
        u32 u0 = H1[(size_t)s0 * 64 + lane];
        ax += w0 * bflo(u0);
        ay += w0 * bfhi(u0);
    }
    ax = fmaxf(ax + b1[lane * 2], 0.f);
    ay = fmaxf(ay + b1[lane * 2 + 1], 0.f);
    A1[(size_t)node * 64 + lane] = pack2(ax, ay);
}

// ---------------- AGG2 (verified R3, pull) + bias + log_softmax ----------------

__global__ __launch_bounds__(256) void k_agg2(const u32* __restrict__ H2, const int* __restrict__ csr,
                                              const int* __restrict__ rowptr, const float* __restrict__ dinv,
                                              const float* __restrict__ b2, float* __restrict__ out, int n) {
    int node = (int)((blockIdx.x * 256 + threadIdx.x) >> 6);
    int lane = threadIdx.x & 63;
    if (node >= n) return;
    bool act = lane < 20;
    int idx = act ? lane : 0;
    float di = dinv[node];
    u32 us = H2[(size_t)node * 32 + idx];
    float wself = di * di;
    float a0 = wself * bflo(us), a1 = wself * bfhi(us);
    int e0 = rowptr[node], e1 = rowptr[node + 1];
    int e = e0;
    for (; e + 1 < e1; e += 2) {
        int s0 = csr[e], s1 = csr[e + 1];
        float w0 = dinv[s0] * di, w1 = dinv[s1] * di;
        u32 u0 = H2[(size_t)s0 * 32 + idx];
        u32 u1 = H2[(size_t)s1 * 32 + idx];
        a0 += w0 * bflo(u0) + w1 * bflo(u1);
        a1 += w0 * bfhi(u0) + w1 * bfhi(u1);
    }
    if (e < e1) {
        int s0 = csr[e];
        float w0 = dinv[s0] * di;
        u32 u0 = H2[(size_t)s0 * 32 + idx];
        a0 += w0 * bflo(u0);
        a1 += w0 * bfhi(u0);
    }
    a0 += b2[idx * 2];
    a1 += b2[idx * 2 + 1];
    float v = act ? fmaxf(a0, a1) : -INFINITY;
#pragma unroll
    for (int off = 32; off > 0; off >>= 1) v = fmaxf(v, __shfl_xor(v, off, 64));
    float ex = act ? (expf(a0 - v) + expf(a1 - v)) : 0.f;
#pragma unroll
    for (int off = 32; off > 0; off >>= 1) ex += __shfl_xor(ex, off, 64);
    float ls = logf(ex);
    if (act) {
        float2 o; o.x = a0 - v - ls; o.y = a1 - v - ls;
        *(float2*)&out[(size_t)node * NCLS + lane * 2] = o;
    }
}

// ---------------- launch ----------------

extern "C" void kernel_launch(void* const* d_in, const int* in_sizes, int n_in,
                              void* d_out, int out_size, void* d_ws, size_t ws_size,
                              hipStream_t stream) {
    const float* X  = (const float*)d_in[0];
    const int*   EI = (const int*)d_in[1];
    const float* W1 = (const float*)d_in[2];
    const float* B1 = (const float*)d_in[3];
    const float* W2 = (const float*)d_in[4];
    const float* B2 = (const float*)d_in[5];
    float* OUT = (float*)d_out;

    const int N = in_sizes[0] / F_INN;        // 100000
    const int E = in_sizes[1] / 2;            // 1600000
    const int nbuck = (N + BUCK_NODES - 1) >> BUCK_SHIFT;   // 782
    const int m = nbuck * NSPLIT;             // 6256 window slots

    char* ws = (char*)d_ws;
    size_t off = 0;
    auto alloc = [&](size_t bytes) -> void* {
        off = (off + 255) & ~(size_t)255;
        void* p = ws + off;
        off += bytes;
        return p;
    };
    u32*   H1     = (u32*)  alloc((size_t)N * 64 * 4);    // 25.6 MB
    u32*   A1     = (u32*)  alloc((size_t)N * 64 * 4);    // 25.6 MB
    u32*   H2     = (u32*)  alloc((size_t)N * 32 * 4);    // 12.8 MB
    float* dinv   = (float*)alloc((size_t)N * 4);
    u32*   gtot   = (u32*)  alloc((size_t)(m + 1) * 4);
    u32*   base   = (u32*)  alloc((size_t)(m + 1) * 4);
    u32*   cursor = (u32*)  alloc((size_t)m * 4);
    u32*   arr    = (u32*)  alloc((size_t)E * 4);         // 6.4 MB packed edges
    int*   csr    = (int*)  alloc((size_t)E * 4);         // 6.4 MB sorted srcs
    int*   rowptr = (int*)  alloc((size_t)(N + 1) * 4);

    hipMemsetAsync(gtot, 0, (size_t)m * 4, stream);

    int nchunk = (E + CHUNK - 1) / CHUNK;     // 196

    k_s1   <<<nchunk, 256, 0, stream>>>(EI, gtot, E, nbuck);
    k_s2   <<<1, 256, 0, stream>>>(gtot, base, cursor, m);
    k_s3   <<<nchunk, 256, 0, stream>>>(EI, cursor, arr, E, nbuck);
    k_sortb<<<nbuck, 256, 0, stream>>>(arr, base, csr, rowptr, dinv, N, nbuck);

    k_gemm1<<<(N + 31) / 32, 256, 0, stream>>>(X, W1, H1, N);
    k_agg1 <<<(N + 3) / 4, 256, 0, stream>>>(H1, csr, rowptr, dinv, B1, A1, N);
    k_gemm2<<<(N + 63) / 64, 256, 0, stream>>>(A1, W2, H2, N);
    k_agg2 <<<(N + 3) / 4, 256, 0, stream>>>(H2, csr, rowptr, dinv, B2, OUT, N);
}

// Round 7
// 378.548 us; speedup vs baseline: 5.4168x; 1.2212x over previous
//
#include <hip/hip_runtime.h>
#include <cstdint>
#include <cmath>

#define F_INN 128
#define HIDD  128
#define NCLS  40

#define BUCK_SHIFT 7
#define BUCK_NODES 128
#define MAXBUCK 1024
#define NSPLIT 8
#define CHUNK 8192

typedef unsigned int u32;
typedef unsigned short u16;
typedef __attribute__((ext_vector_type(8))) short bf16x8;
typedef __attribute__((ext_vector_type(4))) float f32x4;

static __device__ __forceinline__ float bflo(u32 u) { return __builtin_bit_cast(float, u << 16); }
static __device__ __forceinline__ float bfhi(u32 u) { return __builtin_bit_cast(float, u & 0xffff0000u); }
static __device__ __forceinline__ u16 f2bf(float f) {
    u32 u = __builtin_bit_cast(u32, f);
    return (u16)((u + 0x7fffu + ((u >> 16) & 1u)) >> 16);
}
static __device__ __forceinline__ u32 pack2(float a, float b) {
    return (u32)f2bf(a) | ((u32)f2bf(b) << 16);
}

// ---------------- S1: per-chunk bucket histogram -> per-(bucket,slot) totals ----------------

__global__ __launch_bounds__(256) void k_s1(const int* __restrict__ ei, u32* __restrict__ gtot,
                                            int E, int nbuck) {
    __shared__ u32 cnt[MAXBUCK];
    int t = threadIdx.x;
    for (int i = t; i < nbuck; i += 256) cnt[i] = 0;
    __syncthreads();
    int x = blockIdx.x & (NSPLIT - 1);
    int e0 = blockIdx.x * CHUNK;
    int n = min(CHUNK, E - e0);
    const int* dst = ei + E;
    for (int i = t; i < n; i += 256)
        atomicAdd(&cnt[dst[e0 + i] >> BUCK_SHIFT], 1u);
    __syncthreads();
    for (int b = t; b < nbuck; b += 256) {
        u32 c = cnt[b];
        if (c) atomicAdd(&gtot[(b << 3) | x], c);
    }
}

// ---------------- S2: exclusive scan ----------------

__global__ __launch_bounds__(256) void k_s2(const u32* __restrict__ gtot, u32* __restrict__ base,
                                            u32* __restrict__ cursor, int m) {
    __shared__ u32 part[256];
    int t = threadIdx.x;
    u32 local[32];
    u32 s = 0;
#pragma unroll
    for (int j = 0; j < 32; ++j) {
        int i = t * 32 + j;
        u32 v = (i < m) ? gtot[i] : 0u;
        local[j] = s;
        s += v;
    }
    part[t] = s;
    __syncthreads();
    for (int off = 1; off < 256; off <<= 1) {
        u32 v = (t >= off) ? part[t - off] : 0u;
        __syncthreads();
        part[t] += v;
        __syncthreads();
    }
    u32 pre = (t == 0) ? 0u : part[t - 1];
#pragma unroll
    for (int j = 0; j < 32; ++j) {
        int i = t * 32 + j;
        if (i < m) { u32 bb = pre + local[j]; base[i] = bb; cursor[i] = bb; }
    }
    if (t == 255) base[m] = part[255];
}

// ---------------- S3: scatter packed edges into bucket sub-windows ----------------

__global__ __launch_bounds__(256) void k_s3(const int* __restrict__ ei, u32* __restrict__ cursor,
                                            u32* __restrict__ arr, int E, int nbuck) {
    __shared__ u32 cnt[MAXBUCK];
    __shared__ u32 lbase[MAXBUCK];
    int t = threadIdx.x;
    for (int i = t; i < nbuck; i += 256) cnt[i] = 0;
    __syncthreads();
    int x = blockIdx.x & (NSPLIT - 1);
    int e0 = blockIdx.x * CHUNK;
    int n = min(CHUNK, E - e0);
    const int* src = ei;
    const int* dst = ei + E;
    for (int i = t; i < n; i += 256)
        atomicAdd(&cnt[dst[e0 + i] >> BUCK_SHIFT], 1u);
    __syncthreads();
    for (int b = t; b < nbuck; b += 256) {
        u32 c = cnt[b];
        lbase[b] = c ? atomicAdd(&cursor[(b << 3) | x], c) : 0u;
    }
    __syncthreads();
    for (int i = t; i < nbuck; i += 256) cnt[i] = 0;
    __syncthreads();
    for (int i = t; i < n; i += 256) {
        int s = src[e0 + i], d = dst[e0 + i];
        int b = d >> BUCK_SHIFT;
        u32 off = atomicAdd(&cnt[b], 1u);
        arr[lbase[b] + off] = ((u32)s << BUCK_SHIFT) | (u32)(d & (BUCK_NODES - 1));
    }
}

// ---------------- SORT: per-bucket counting sort -> dense csr + rowptr + dinv ----------------

__global__ __launch_bounds__(256) void k_sortb(const u32* __restrict__ arr, const u32* __restrict__ base,
                                               int* __restrict__ csr, int* __restrict__ rowptr,
                                               float* __restrict__ dinv, int N, int nbuck) {
    __shared__ u32 cnt[BUCK_NODES];
    __shared__ u32 ex[BUCK_NODES];
    __shared__ u32 cur[BUCK_NODES];
    int b = blockIdx.x, t = threadIdx.x;
    int node0 = b << BUCK_SHIFT;
    if (t < BUCK_NODES) cnt[t] = 0;
    __syncthreads();
    u32 s0 = base[b << 3], s1 = base[(b + 1) << 3];
    for (u32 i = s0 + t; i < s1; i += 256)
        atomicAdd(&cnt[arr[i] & (u32)(BUCK_NODES - 1)], 1u);
    __syncthreads();
    if (t < BUCK_NODES) ex[t] = cnt[t];
    __syncthreads();
    for (int off = 1; off < BUCK_NODES; off <<= 1) {
        u32 v = 0;
        if (t < BUCK_NODES && t >= off) v = ex[t - off];
        __syncthreads();
        if (t < BUCK_NODES) ex[t] += v;
        __syncthreads();
    }
    if (t < BUCK_NODES) {
        int node = node0 + t;
        u32 excl = ex[t] - cnt[t];
        cur[t] = s0 + excl;
        if (node <= N) rowptr[node] = (int)(s0 + excl);
        if (node < N) dinv[node] = rsqrtf((float)(cnt[t] + 1));
    }
    if (t == 0 && b == nbuck - 1) rowptr[N] = (int)s1;
    __syncthreads();
    for (u32 i = s0 + t; i < s1; i += 256) {
        u32 pk = arr[i];
        int d = (int)(pk & (u32)(BUCK_NODES - 1));
        u32 pos = atomicAdd(&cur[d], 1u);
        csr[pos] = (int)(pk >> BUCK_SHIFT);
    }
}

// ---------------- GEMM1 (MFMA): H1 = bf16( X @ W1 ) ----------------
// 128 rows/block, 4 waves x (32 rows x 128 cols). LDS xa/wb bf16-pairs with
// XOR swizzle (c ^= (row&7)<<2 on u32 index) -> 2-way conflict ds_read_b128 (free).

__global__ __launch_bounds__(256) void k_gemm1m(const float* __restrict__ X, const float* __restrict__ W,
                                                u32* __restrict__ H, int M) {
    __shared__ u32 xa[128 * 64];
    __shared__ u32 wb[128 * 64];
    int tid = threadIdx.x;
    int row0 = blockIdx.x * 128;
    // stage W^T: wb[n][kp] = pack(W[2kp][n], W[2kp+1][n])
    for (int j = tid; j < 64 * 128; j += 256) {
        int n = j & 127, kp = j >> 7;
        u32 v = pack2(W[(2 * kp) * 128 + n], W[(2 * kp + 1) * 128 + n]);
        wb[n * 64 + (kp ^ ((n & 7) << 2))] = v;
    }
    // stage X -> bf16 pairs
    for (int j = tid; j < 128 * 64; j += 256) {
        int r = j >> 6, c = j & 63;
        int gr = row0 + r;
        u32 v = 0;
        if (gr < M) {
            float2 xv = *(const float2*)&X[(size_t)gr * 128 + 2 * c];
            v = pack2(xv.x, xv.y);
        }
        xa[r * 64 + (c ^ ((r & 7) << 2))] = v;
    }
    __syncthreads();
    int lane = tid & 63, wv = tid >> 6;
    int rw = wv * 32;
    int lr = lane & 15, lg = lane >> 4;
    f32x4 acc[2][8] = {};
    for (int kk = 0; kk < 4; ++kk) {
        int c0 = kk * 16 + lg * 4;
        int ra0 = rw + lr, ra1 = rw + 16 + lr;
        bf16x8 a0 = *(const bf16x8*)&xa[ra0 * 64 + (c0 ^ ((ra0 & 7) << 2))];
        bf16x8 a1 = *(const bf16x8*)&xa[ra1 * 64 + (c0 ^ ((ra1 & 7) << 2))];
#pragma unroll
        for (int nf = 0; nf < 8; ++nf) {
            int bn = nf * 16 + lr;
            bf16x8 bfr = *(const bf16x8*)&wb[bn * 64 + (c0 ^ ((bn & 7) << 2))];
            acc[0][nf] = __builtin_amdgcn_mfma_f32_16x16x32_bf16(a0, bfr, acc[0][nf], 0, 0, 0);
            acc[1][nf] = __builtin_amdgcn_mfma_f32_16x16x32_bf16(a1, bfr, acc[1][nf], 0, 0, 0);
        }
    }
    // C/D layout: col = lane&15, row = (lane>>4)*4 + reg
    u16* Hs = (u16*)H;
#pragma unroll
    for (int rf = 0; rf < 2; ++rf) {
#pragma unroll
        for (int nf = 0; nf < 8; ++nf) {
            int col = nf * 16 + lr;
#pragma unroll
            for (int j = 0; j < 4; ++j) {
                int gr = row0 + rw + rf * 16 + lg * 4 + j;
                if (gr < M) Hs[(size_t)gr * 128 + col] = f2bf(acc[rf][nf][j]);
            }
        }
    }
}

// ---------------- GEMM2 (MFMA): H2 = bf16( A1 @ W2 ), N=40 padded to 48 ----------------

__global__ __launch_bounds__(256) void k_gemm2m(const u32* __restrict__ A, const float* __restrict__ W,
                                                u32* __restrict__ H, int M) {
    __shared__ u32 xa[128 * 64];
    __shared__ u32 wb[48 * 64];
    int tid = threadIdx.x;
    int row0 = blockIdx.x * 128;
    for (int j = tid; j < 64 * 64; j += 256) {
        int n = j & 63, kp = j >> 6;
        if (n < 48) {
            u32 v = 0;
            if (n < 40) v = pack2(W[(2 * kp) * 40 + n], W[(2 * kp + 1) * 40 + n]);
            wb[n * 64 + (kp ^ ((n & 7) << 2))] = v;
        }
    }
    for (int j = tid; j < 128 * 64; j += 256) {
        int r = j >> 6, c = j & 63;
        int gr = row0 + r;
        u32 v = (gr < M) ? A[(size_t)gr * 64 + c] : 0u;
        xa[r * 64 + (c ^ ((r & 7) << 2))] = v;
    }
    __syncthreads();
    int lane = tid & 63, wv = tid >> 6;
    int rw = wv * 32;
    int lr = lane & 15, lg = lane >> 4;
    f32x4 acc[2][3] = {};
    for (int kk = 0; kk < 4; ++kk) {
        int c0 = kk * 16 + lg * 4;
        int ra0 = rw + lr, ra1 = rw + 16 + lr;
        bf16x8 a0 = *(const bf16x8*)&xa[ra0 * 64 + (c0 ^ ((ra0 & 7) << 2))];
        bf16x8 a1 = *(const bf16x8*)&xa[ra1 * 64 + (c0 ^ ((ra1 & 7) << 2))];
#pragma unroll
        for (int nf = 0; nf < 3; ++nf) {
            int bn = nf * 16 + lr;
            bf16x8 bfr = *(const bf16x8*)&wb[bn * 64 + (c0 ^ ((bn & 7) << 2))];
            acc[0][nf] = __builtin_amdgcn_mfma_f32_16x16x32_bf16(a0, bfr, acc[0][nf], 0, 0, 0);
            acc[1][nf] = __builtin_amdgcn_mfma_f32_16x16x32_bf16(a1, bfr, acc[1][nf], 0, 0, 0);
        }
    }
    u16* Hs = (u16*)H;
#pragma unroll
    for (int rf = 0; rf < 2; ++rf) {
#pragma unroll
        for (int nf = 0; nf < 3; ++nf) {
            int col = nf * 16 + lr;
            if (col < 40) {
#pragma unroll
                for (int j = 0; j < 4; ++j) {
                    int gr = row0 + rw + rf * 16 + lg * 4 + j;
                    if (gr < M) Hs[(size_t)gr * 64 + col] = f2bf(acc[rf][nf][j]);
                }
            }
        }
    }
}

// ---------------- AGG1 (pull, unroll x4): A1 = bf16(relu(Ahat @ H1 + b1)) ----------------

__global__ __launch_bounds__(256) void k_agg1(const u32* __restrict__ H1, const int* __restrict__ csr,
                                              const int* __restrict__ rowptr, const float* __restrict__ dinv,
                                              const float* __restrict__ b1, u32* __restrict__ A1, int n) {
    int node = (int)((blockIdx.x * 256 + threadIdx.x) >> 6);
    int lane = threadIdx.x & 63;
    if (node >= n) return;
    float di = dinv[node];
    u32 us = H1[(size_t)node * 64 + lane];
    float wself = di * di;
    float ax = wself * bflo(us), ay = wself * bfhi(us);
    int e0 = rowptr[node], e1 = rowptr[node + 1];
    int e = e0;
    for (; e + 3 < e1; e += 4) {
        int s0 = csr[e], s1 = csr[e + 1], s2 = csr[e + 2], s3 = csr[e + 3];
        float w0 = dinv[s0] * di, w1 = dinv[s1] * di, w2 = dinv[s2] * di, w3 = dinv[s3] * di;
        u32 u0 = H1[(size_t)s0 * 64 + lane];
        u32 u1 = H1[(size_t)s1 * 64 + lane];
        u32 u2 = H1[(size_t)s2 * 64 + lane];
        u32 u3 = H1[(size_t)s3 * 64 + lane];
        ax += w0 * bflo(u0) + w1 * bflo(u1) + w2 * bflo(u2) + w3 * bflo(u3);
        ay += w0 * bfhi(u0) + w1 * bfhi(u1) + w2 * bfhi(u2) + w3 * bfhi(u3);
    }
    for (; e < e1; ++e) {
        int s0 = csr[e];
        float w0 = dinv[s0] * di;
        u32 u0 = H1[(size_t)s0 * 64 + lane];
        ax += w0 * bflo(u0);
        ay += w0 * bfhi(u0);
    }
    ax = fmaxf(ax + b1[lane * 2], 0.f);
    ay = fmaxf(ay + b1[lane * 2 + 1], 0.f);
    A1[(size_t)node * 64 + lane] = pack2(ax, ay);
}

// ---------------- AGG2 (pull, 2 nodes/wave) + bias + log_softmax ----------------
// half-wave per node: lanes l<20 own 2 classes each; reductions confined to 32-lane halves.

__global__ __launch_bounds__(256) void k_agg2(const u32* __restrict__ H2, const int* __restrict__ csr,
                                              const int* __restrict__ rowptr, const float* __restrict__ dinv,
                                              const float* __restrict__ b2, float* __restrict__ out, int n) {
    int wid = (int)((blockIdx.x * 256 + threadIdx.x) >> 6);
    int lane = threadIdx.x & 63;
    int half = lane >> 5, l = lane & 31;
    int node = wid * 2 + half;
    int nc = (node < n) ? node : (n - 1);
    bool wr = (l < 20) && (node < n);
    int idx = (l < 20) ? l : 0;
    float di = dinv[nc];
    u32 us = H2[(size_t)nc * 32 + idx];
    float wself = di * di;
    float a0 = wself * bflo(us), a1 = wself * bfhi(us);
    int e0 = rowptr[nc], e1 = rowptr[nc + 1];
    int e = e0;
    for (; e + 1 < e1; e += 2) {
        int s0 = csr[e], s1 = csr[e + 1];
        float w0 = dinv[s0] * di, w1 = dinv[s1] * di;
        u32 u0 = H2[(size_t)s0 * 32 + idx];
        u32 u1 = H2[(size_t)s1 * 32 + idx];
        a0 += w0 * bflo(u0) + w1 * bflo(u1);
        a1 += w0 * bfhi(u0) + w1 * bfhi(u1);
    }
    if (e < e1) {
        int s0 = csr[e];
        float w0 = dinv[s0] * di;
        u32 u0 = H2[(size_t)s0 * 32 + idx];
        a0 += w0 * bflo(u0);
        a1 += w0 * bfhi(u0);
    }
    a0 += b2[idx * 2];
    a1 += b2[idx * 2 + 1];
    float v = (l < 20) ? fmaxf(a0, a1) : -INFINITY;
#pragma unroll
    for (int off = 16; off > 0; off >>= 1) v = fmaxf(v, __shfl_xor(v, off, 64));
    float ex = (l < 20) ? (expf(a0 - v) + expf(a1 - v)) : 0.f;
#pragma unroll
    for (int off = 16; off > 0; off >>= 1) ex += __shfl_xor(ex, off, 64);
    float ls = logf(ex);
    if (wr) {
        float2 o; o.x = a0 - v - ls; o.y = a1 - v - ls;
        *(float2*)&out[(size_t)node * NCLS + l * 2] = o;
    }
}

// ---------------- launch ----------------

extern "C" void kernel_launch(void* const* d_in, const int* in_sizes, int n_in,
                              void* d_out, int out_size, void* d_ws, size_t ws_size,
                              hipStream_t stream) {
    const float* X  = (const float*)d_in[0];
    const int*   EI = (const int*)d_in[1];
    const float* W1 = (const float*)d_in[2];
    const float* B1 = (const float*)d_in[3];
    const float* W2 = (const float*)d_in[4];
    const float* B2 = (const float*)d_in[5];
    float* OUT = (float*)d_out;

    const int N = in_sizes[0] / F_INN;        // 100000
    const int E = in_sizes[1] / 2;            // 1600000
    const int nbuck = (N + BUCK_NODES - 1) >> BUCK_SHIFT;   // 782
    const int m = nbuck * NSPLIT;

    char* ws = (char*)d_ws;
    size_t off = 0;
    auto alloc = [&](size_t bytes) -> void* {
        off = (off + 255) & ~(size_t)255;
        void* p = ws + off;
        off += bytes;
        return p;
    };
    u32*   H1     = (u32*)  alloc((size_t)N * 64 * 4);
    u32*   A1     = (u32*)  alloc((size_t)N * 64 * 4);
    u32*   H2     = (u32*)  alloc((size_t)N * 32 * 4);
    float* dinv   = (float*)alloc((size_t)N * 4);
    u32*   gtot   = (u32*)  alloc((size_t)(m + 1) * 4);
    u32*   base   = (u32*)  alloc((size_t)(m + 1) * 4);
    u32*   cursor = (u32*)  alloc((size_t)m * 4);
    u32*   arr    = (u32*)  alloc((size_t)E * 4);
    int*   csr    = (int*)  alloc((size_t)E * 4);
    int*   rowptr = (int*)  alloc((size_t)(N + 1) * 4);

    hipMemsetAsync(gtot, 0, (size_t)m * 4, stream);

    int nchunk = (E + CHUNK - 1) / CHUNK;

    k_s1   <<<nchunk, 256, 0, stream>>>(EI, gtot, E, nbuck);
    k_s2   <<<1, 256, 0, stream>>>(gtot, base, cursor, m);
    k_s3   <<<nchunk, 256, 0, stream>>>(EI, cursor, arr, E, nbuck);
    k_sortb<<<nbuck, 256, 0, stream>>>(arr, base, csr, rowptr, dinv, N, nbuck);

    int gblk = (N + 127) / 128;               // 782
    k_gemm1m<<<gblk, 256, 0, stream>>>(X, W1, H1, N);
    k_agg1  <<<(N + 3) / 4, 256, 0, stream>>>(H1, csr, rowptr, dinv, B1, A1, N);
    k_gemm2m<<<gblk, 256, 0, stream>>>(A1, W2, H2, N);
    int nw = (N + 1) / 2;
    k_agg2  <<<(nw + 3) / 4, 256, 0, stream>>>(H2, csr, rowptr, dinv, B2, OUT, N);
}

// Round 10
// 367.777 us; speedup vs baseline: 5.5754x; 1.0293x over previous
//
#include <hip/hip_runtime.h>
#include <cstdint>
#include <cmath>

#define F_INN 128
#define HIDD  128
#define NCLS  40

#define BUCK_SHIFT 7
#define BUCK_NODES 128
#define MAXBUCK 1024
#define NSPLIT 8
#define CHUNK 8192

typedef unsigned int u32;
typedef unsigned short u16;
typedef __attribute__((ext_vector_type(8))) short bf16x8;
typedef __attribute__((ext_vector_type(4))) float f32x4;

static __device__ __forceinline__ float bflo(u32 u) { return __builtin_bit_cast(float, u << 16); }
static __device__ __forceinline__ float bfhi(u32 u) { return __builtin_bit_cast(float, u & 0xffff0000u); }
static __device__ __forceinline__ u16 f2bf(float f) {
    u32 u = __builtin_bit_cast(u32, f);
    return (u16)((u + 0x7fffu + ((u >> 16) & 1u)) >> 16);
}
static __device__ __forceinline__ u32 pack2(float a, float b) {
    return (u32)f2bf(a) | ((u32)f2bf(b) << 16);
}

// ---------------- S1: per-chunk bucket histogram -> per-(bucket,slot) totals ----------------

__global__ __launch_bounds__(256) void k_s1(const int* __restrict__ ei, u32* __restrict__ gtot,
                                            int E, int nbuck) {
    __shared__ u32 cnt[MAXBUCK];
    int t = threadIdx.x;
    for (int i = t; i < nbuck; i += 256) cnt[i] = 0;
    __syncthreads();
    int x = blockIdx.x & (NSPLIT - 1);
    int e0 = blockIdx.x * CHUNK;
    int n = min(CHUNK, E - e0);
    const int* dst = ei + E;
    for (int i = t; i < n; i += 256)
        atomicAdd(&cnt[dst[e0 + i] >> BUCK_SHIFT], 1u);
    __syncthreads();
    for (int b = t; b < nbuck; b += 256) {
        u32 c = cnt[b];
        if (c) atomicAdd(&gtot[(b << 3) | x], c);
    }
}

// ---------------- S2: exclusive scan ----------------

__global__ __launch_bounds__(256) void k_s2(const u32* __restrict__ gtot, u32* __restrict__ base,
                                            u32* __restrict__ cursor, int m) {
    __shared__ u32 part[256];
    int t = threadIdx.x;
    u32 local[32];
    u32 s = 0;
#pragma unroll
    for (int j = 0; j < 32; ++j) {
        int i = t * 32 + j;
        u32 v = (i < m) ? gtot[i] : 0u;
        local[j] = s;
        s += v;
    }
    part[t] = s;
    __syncthreads();
    for (int off = 1; off < 256; off <<= 1) {
        u32 v = (t >= off) ? part[t - off] : 0u;
        __syncthreads();
        part[t] += v;
        __syncthreads();
    }
    u32 pre = (t == 0) ? 0u : part[t - 1];
#pragma unroll
    for (int j = 0; j < 32; ++j) {
        int i = t * 32 + j;
        if (i < m) { u32 bb = pre + local[j]; base[i] = bb; cursor[i] = bb; }
    }
    if (t == 255) base[m] = part[255];
}

// ---------------- S3: scatter packed edges into bucket sub-windows ----------------

__global__ __launch_bounds__(256) void k_s3(const int* __restrict__ ei, u32* __restrict__ cursor,
                                            u32* __restrict__ arr, int E, int nbuck) {
    __shared__ u32 cnt[MAXBUCK];
    __shared__ u32 lbase[MAXBUCK];
    int t = threadIdx.x;
    for (int i = t; i < nbuck; i += 256) cnt[i] = 0;
    __syncthreads();
    int x = blockIdx.x & (NSPLIT - 1);
    int e0 = blockIdx.x * CHUNK;
    int n = min(CHUNK, E - e0);
    const int* src = ei;
    const int* dst = ei + E;
    for (int i = t; i < n; i += 256)
        atomicAdd(&cnt[dst[e0 + i] >> BUCK_SHIFT], 1u);
    __syncthreads();
    for (int b = t; b < nbuck; b += 256) {
        u32 c = cnt[b];
        lbase[b] = c ? atomicAdd(&cursor[(b << 3) | x], c) : 0u;
    }
    __syncthreads();
    for (int i = t; i < nbuck; i += 256) cnt[i] = 0;
    __syncthreads();
    for (int i = t; i < n; i += 256) {
        int s = src[e0 + i], d = dst[e0 + i];
        int b = d >> BUCK_SHIFT;
        u32 off = atomicAdd(&cnt[b], 1u);
        arr[lbase[b] + off] = ((u32)s << BUCK_SHIFT) | (u32)(d & (BUCK_NODES - 1));
    }
}

// ---------------- SORT: per-bucket counting sort -> dense csr + rowptr + dinv ----------------

__global__ __launch_bounds__(256) void k_sortb(const u32* __restrict__ arr, const u32* __restrict__ base,
                                               int* __restrict__ csr, int* __restrict__ rowptr,
                                               float* __restrict__ dinv, int N, int nbuck) {
    __shared__ u32 cnt[BUCK_NODES];
    __shared__ u32 ex[BUCK_NODES];
    __shared__ u32 cur[BUCK_NODES];
    int b = blockIdx.x, t = threadIdx.x;
    int node0 = b << BUCK_SHIFT;
    if (t < BUCK_NODES) cnt[t] = 0;
    __syncthreads();
    u32 s0 = base[b << 3], s1 = base[(b + 1) << 3];
    for (u32 i = s0 + t; i < s1; i += 256)
        atomicAdd(&cnt[arr[i] & (u32)(BUCK_NODES - 1)], 1u);
    __syncthreads();
    if (t < BUCK_NODES) ex[t] = cnt[t];
    __syncthreads();
    for (int off = 1; off < BUCK_NODES; off <<= 1) {
        u32 v = 0;
        if (t < BUCK_NODES && t >= off) v = ex[t - off];
        __syncthreads();
        if (t < BUCK_NODES) ex[t] += v;
        __syncthreads();
    }
    if (t < BUCK_NODES) {
        int node = node0 + t;
        u32 excl = ex[t] - cnt[t];
        cur[t] = s0 + excl;
        if (node <= N) rowptr[node] = (int)(s0 + excl);
        if (node < N) dinv[node] = rsqrtf((float)(cnt[t] + 1));
    }
    if (t == 0 && b == nbuck - 1) rowptr[N] = (int)s1;
    __syncthreads();
    for (u32 i = s0 + t; i < s1; i += 256) {
        u32 pk = arr[i];
        int d = (int)(pk & (u32)(BUCK_NODES - 1));
        u32 pos = atomicAdd(&cur[d], 1u);
        csr[pos] = (int)(pk >> BUCK_SHIFT);
    }
}

// ---------------- GEMM1 (MFMA): H1' = bf16( dinv[r] * (X @ W1) ) ----------------
// premultiplied by dinv so agg1's inner loop is pure adds.

__global__ __launch_bounds__(256) void k_gemm1m(const float* __restrict__ X, const float* __restrict__ W,
                                                const float* __restrict__ dinv,
                                                u32* __restrict__ H, int M) {
    __shared__ u32 xa[128 * 64];
    __shared__ u32 wb[128 * 64];
    int tid = threadIdx.x;
    int row0 = blockIdx.x * 128;
    for (int j = tid; j < 64 * 128; j += 256) {
        int n = j & 127, kp = j >> 7;
        u32 v = pack2(W[(2 * kp) * 128 + n], W[(2 * kp + 1) * 128 + n]);
        wb[n * 64 + (kp ^ ((n & 7) << 2))] = v;
    }
    for (int j = tid; j < 128 * 64; j += 256) {
        int r = j >> 6, c = j & 63;
        int gr = row0 + r;
        u32 v = 0;
        if (gr < M) {
            float2 xv = *(const float2*)&X[(size_t)gr * 128 + 2 * c];
            v = pack2(xv.x, xv.y);
        }
        xa[r * 64 + (c ^ ((r & 7) << 2))] = v;
    }
    __syncthreads();
    int lane = tid & 63, wv = tid >> 6;
    int rw = wv * 32;
    int lr = lane & 15, lg = lane >> 4;
    f32x4 acc[2][8] = {};
    for (int kk = 0; kk < 4; ++kk) {
        int c0 = kk * 16 + lg * 4;
        int ra0 = rw + lr, ra1 = rw + 16 + lr;
        bf16x8 a0 = *(const bf16x8*)&xa[ra0 * 64 + (c0 ^ ((ra0 & 7) << 2))];
        bf16x8 a1 = *(const bf16x8*)&xa[ra1 * 64 + (c0 ^ ((ra1 & 7) << 2))];
#pragma unroll
        for (int nf = 0; nf < 8; ++nf) {
            int bn = nf * 16 + lr;
            bf16x8 bfr = *(const bf16x8*)&wb[bn * 64 + (c0 ^ ((bn & 7) << 2))];
            acc[0][nf] = __builtin_amdgcn_mfma_f32_16x16x32_bf16(a0, bfr, acc[0][nf], 0, 0, 0);
            acc[1][nf] = __builtin_amdgcn_mfma_f32_16x16x32_bf16(a1, bfr, acc[1][nf], 0, 0, 0);
        }
    }
    // per-row dinv scale factors for this lane's output rows
    float drow[2][4];
#pragma unroll
    for (int rf = 0; rf < 2; ++rf)
#pragma unroll
        for (int j = 0; j < 4; ++j) {
            int gr = row0 + rw + rf * 16 + lg * 4 + j;
            drow[rf][j] = (gr < M) ? dinv[gr] : 0.f;
        }
    u16* Hs = (u16*)H;
#pragma unroll
    for (int rf = 0; rf < 2; ++rf) {
#pragma unroll
        for (int nf = 0; nf < 8; ++nf) {
            int col = nf * 16 + lr;
#pragma unroll
            for (int j = 0; j < 4; ++j) {
                int gr = row0 + rw + rf * 16 + lg * 4 + j;
                if (gr < M) Hs[(size_t)gr * 128 + col] = f2bf(acc[rf][nf][j] * drow[rf][j]);
            }
        }
    }
}

// ---------------- GEMM2 (MFMA): H2' = bf16( A1' @ W2 )  (scale inherited from A1') ----------------

__global__ __launch_bounds__(256) void k_gemm2m(const u32* __restrict__ A, const float* __restrict__ W,
                                                u32* __restrict__ H, int M) {
    __shared__ u32 xa[128 * 64];
    __shared__ u32 wb[48 * 64];
    int tid = threadIdx.x;
    int row0 = blockIdx.x * 128;
    for (int j = tid; j < 64 * 64; j += 256) {
        int n = j & 63, kp = j >> 6;
        if (n < 48) {
            u32 v = 0;
            if (n < 40) v = pack2(W[(2 * kp) * 40 + n], W[(2 * kp + 1) * 40 + n]);
            wb[n * 64 + (kp ^ ((n & 7) << 2))] = v;
        }
    }
    for (int j = tid; j < 128 * 64; j += 256) {
        int r = j >> 6, c = j & 63;
        int gr = row0 + r;
        u32 v = (gr < M) ? A[(size_t)gr * 64 + c] : 0u;
        xa[r * 64 + (c ^ ((r & 7) << 2))] = v;
    }
    __syncthreads();
    int lane = tid & 63, wv = tid >> 6;
    int rw = wv * 32;
    int lr = lane & 15, lg = lane >> 4;
    f32x4 acc[2][3] = {};
    for (int kk = 0; kk < 4; ++kk) {
        int c0 = kk * 16 + lg * 4;
        int ra0 = rw + lr, ra1 = rw + 16 + lr;
        bf16x8 a0 = *(const bf16x8*)&xa[ra0 * 64 + (c0 ^ ((ra0 & 7) << 2))];
        bf16x8 a1 = *(const bf16x8*)&xa[ra1 * 64 + (c0 ^ ((ra1 & 7) << 2))];
#pragma unroll
        for (int nf = 0; nf < 3; ++nf) {
            int bn = nf * 16 + lr;
            bf16x8 bfr = *(const bf16x8*)&wb[bn * 64 + (c0 ^ ((bn & 7) << 2))];
            acc[0][nf] = __builtin_amdgcn_mfma_f32_16x16x32_bf16(a0, bfr, acc[0][nf], 0, 0, 0);
            acc[1][nf] = __builtin_amdgcn_mfma_f32_16x16x32_bf16(a1, bfr, acc[1][nf], 0, 0, 0);
        }
    }
    u16* Hs = (u16*)H;
#pragma unroll
    for (int rf = 0; rf < 2; ++rf) {
#pragma unroll
        for (int nf = 0; nf < 3; ++nf) {
            int col = nf * 16 + lr;
            if (col < 40) {
#pragma unroll
                for (int j = 0; j < 4; ++j) {
                    int gr = row0 + rw + rf * 16 + lg * 4 + j;
                    if (gr < M) Hs[(size_t)gr * 64 + col] = f2bf(acc[rf][nf][j]);
                }
            }
        }
    }
}

// ---------------- AGG1 (pull, premult, unroll x8): A1' = dinv*bf16(relu(dinv*Sum + b1)) ----------------

__global__ __launch_bounds__(256) void k_agg1(const u32* __restrict__ H1, const int* __restrict__ csr,
                                              const int* __restrict__ rowptr, const float* __restrict__ dinv,
                                              const float* __restrict__ b1, u32* __restrict__ A1, int n) {
    int node = (int)((blockIdx.x * 256 + threadIdx.x) >> 6);
    int lane = threadIdx.x & 63;
    if (node >= n) return;
    float di = dinv[node];
    u32 us = H1[(size_t)node * 64 + lane];
    float ax = bflo(us), ay = bfhi(us);    // self term: H1'[d] (contains dinv_d)
    int e0 = rowptr[node], e1 = rowptr[node + 1];
    int e = e0;
    for (; e + 7 < e1; e += 8) {
        int s0 = csr[e], s1 = csr[e + 1], s2 = csr[e + 2], s3 = csr[e + 3];
        int s4 = csr[e + 4], s5 = csr[e + 5], s6 = csr[e + 6], s7 = csr[e + 7];
        u32 u0 = H1[(size_t)s0 * 64 + lane];
        u32 u1 = H1[(size_t)s1 * 64 + lane];
        u32 u2 = H1[(size_t)s2 * 64 + lane];
        u32 u3 = H1[(size_t)s3 * 64 + lane];
        u32 u4 = H1[(size_t)s4 * 64 + lane];
        u32 u5 = H1[(size_t)s5 * 64 + lane];
        u32 u6 = H1[(size_t)s6 * 64 + lane];
        u32 u7 = H1[(size_t)s7 * 64 + lane];
        ax += ((bflo(u0) + bflo(u1)) + (bflo(u2) + bflo(u3)))
            + ((bflo(u4) + bflo(u5)) + (bflo(u6) + bflo(u7)));
        ay += ((bfhi(u0) + bfhi(u1)) + (bfhi(u2) + bfhi(u3)))
            + ((bfhi(u4) + bfhi(u5)) + (bfhi(u6) + bfhi(u7)));
    }
    for (; e < e1; ++e) {
        int s0 = csr[e];
        u32 u0 = H1[(size_t)s0 * 64 + lane];
        ax += bflo(u0);
        ay += bfhi(u0);
    }
    float2 bb = *(const float2*)&b1[lane * 2];
    ax = fmaxf(di * ax + bb.x, 0.f) * di;   // trailing *di premultiplies A1 for layer 2
    ay = fmaxf(di * ay + bb.y, 0.f) * di;
    A1[(size_t)node * 64 + lane] = pack2(ax, ay);
}

// ---------------- AGG2 (pull, premult, 2 nodes/wave, unroll x4) + bias + log_softmax ----------------

__global__ __launch_bounds__(256) void k_agg2(const u32* __restrict__ H2, const int* __restrict__ csr,
                                              const int* __restrict__ rowptr, const float* __restrict__ dinv,
                                              const float* __restrict__ b2, float* __restrict__ out, int n) {
    int wid = (int)((blockIdx.x * 256 + threadIdx.x) >> 6);
    int lane = threadIdx.x & 63;
    int half = lane >> 5, l = lane & 31;
    int node = wid * 2 + half;
    int nc = (node < n) ? node : (n - 1);
    bool wr = (l < 20) && (node < n);
    int idx = (l < 20) ? l : 0;
    float di = dinv[nc];
    u32 us = H2[(size_t)nc * 32 + idx];
    float a0 = bflo(us), a1 = bfhi(us);    // self term: H2'[d]
    int e0 = rowptr[nc], e1 = rowptr[nc + 1];
    int e = e0;
    for (; e + 3 < e1; e += 4) {
        int s0 = csr[e], s1 = csr[e + 1], s2 = csr[e + 2], s3 = csr[e + 3];
        u32 u0 = H2[(size_t)s0 * 32 + idx];
        u32 u1 = H2[(size_t)s1 * 32 + idx];
        u32 u2 = H2[(size_t)s2 * 32 + idx];
        u32 u3 = H2[(size_t)s3 * 32 + idx];
        a0 += (bflo(u0) + bflo(u1)) + (bflo(u2) + bflo(u3));
        a1 += (bfhi(u0) + bfhi(u1)) + (bfhi(u2) + bfhi(u3));
    }
    for (; e < e1; ++e) {
        int s0 = csr[e];
        u32 u0 = H2[(size_t)s0 * 32 + idx];
        a0 += bflo(u0);
        a1 += bfhi(u0);
    }
    a0 = di * a0 + b2[idx * 2];
    a1 = di * a1 + b2[idx * 2 + 1];
    float v = (l < 20) ? fmaxf(a0, a1) : -INFINITY;
#pragma unroll
    for (int off = 16; off > 0; off >>= 1) v = fmaxf(v, __shfl_xor(v, off, 64));
    float ex = (l < 20) ? (expf(a0 - v) + expf(a1 - v)) : 0.f;
#pragma unroll
    for (int off = 16; off > 0; off >>= 1) ex += __shfl_xor(ex, off, 64);
    float ls = logf(ex);
    if (wr) {
        float2 o; o.x = a0 - v - ls; o.y = a1 - v - ls;
        *(float2*)&out[(size_t)node * NCLS + l * 2] = o;
    }
}

// ---------------- launch ----------------

extern "C" void kernel_launch(void* const* d_in, const int* in_sizes, int n_in,
                              void* d_out, int out_size, void* d_ws, size_t ws_size,
                              hipStream_t stream) {
    const float* X  = (const float*)d_in[0];
    const int*   EI = (const int*)d_in[1];
    const float* W1 = (const float*)d_in[2];
    const float* B1 = (const float*)d_in[3];
    const float* W2 = (const float*)d_in[4];
    const float* B2 = (const float*)d_in[5];
    float* OUT = (float*)d_out;

    const int N = in_sizes[0] / F_INN;        // 100000
    const int E = in_sizes[1] / 2;            // 1600000
    const int nbuck = (N + BUCK_NODES - 1) >> BUCK_SHIFT;   // 782
    const int m = nbuck * NSPLIT;

    char* ws = (char*)d_ws;
    size_t off = 0;
    auto alloc = [&](size_t bytes) -> void* {
        off = (off + 255) & ~(size_t)255;
        void* p = ws + off;
        off += bytes;
        return p;
    };
    u32*   H1     = (u32*)  alloc((size_t)N * 64 * 4);
    u32*   A1     = (u32*)  alloc((size_t)N * 64 * 4);
    u32*   H2     = (u32*)  alloc((size_t)N * 32 * 4);
    float* dinv   = (float*)alloc((size_t)N * 4);
    u32*   gtot   = (u32*)  alloc((size_t)(m + 1) * 4);
    u32*   base   = (u32*)  alloc((size_t)(m + 1) * 4);
    u32*   cursor = (u32*)  alloc((size_t)m * 4);
    u32*   arr    = (u32*)  alloc((size_t)E * 4);
    int*   csr    = (int*)  alloc((size_t)E * 4);
    int*   rowptr = (int*)  alloc((size_t)(N + 1) * 4);

    hipMemsetAsync(gtot, 0, (size_t)m * 4, stream);

    int nchunk = (E + CHUNK - 1) / CHUNK;

    k_s1   <<<nchunk, 256, 0, stream>>>(EI, gtot, E, nbuck);
    k_s2   <<<1, 256, 0, stream>>>(gtot, base, cursor, m);
    k_s3   <<<nchunk, 256, 0, stream>>>(EI, cursor, arr, E, nbuck);
    k_sortb<<<nbuck, 256, 0, stream>>>(arr, base, csr, rowptr, dinv, N, nbuck);

    int gblk = (N + 127) / 128;               // 782
    k_gemm1m<<<gblk, 256, 0, stream>>>(X, W1, dinv, H1, N);
    k_agg1  <<<(N + 3) / 4, 256, 0, stream>>>(H1, csr, rowptr, dinv, B1, A1, N);
    k_gemm2m<<<gblk, 256, 0, stream>>>(A1, W2, H2, N);
    int nw = (N + 1) / 2;
    k_agg2  <<<(nw + 3) / 4, 256, 0, stream>>>(H2, csr, rowptr, dinv, B2, OUT, N);
}